// Round 2
// baseline (275.020 us; speedup 1.0000x reference)
//
#include <hip/hip_runtime.h>
#include <hip/hip_bf16.h>
#include <stdint.h>

#define M_TOK 32
#define IN_F 4096
#define OUT_F 11008
#define NSPLIT 8
#define KRANGE (IN_F / NSPLIT)   // 512 k per block
#define NSTEP  (KRANGE / 32)     // 16 MFMA k-steps per block
#define NKK    (IN_F / 32)       // 128 global k-steps

typedef __attribute__((ext_vector_type(8))) short bf16x8;
typedef __attribute__((ext_vector_type(4))) float f32x4;

__device__ inline uint32_t pack_bf16(float a, float b) {
    __hip_bfloat16 ha = __float2bfloat16(a);
    __hip_bfloat16 hb = __float2bfloat16(b);
    uint16_t ua = *(uint16_t*)&ha;
    uint16_t ub = *(uint16_t*)&hb;
    return (uint32_t)ua | ((uint32_t)ub << 16);
}

// out[m][o] = bias[o]   (grid: 43 x 32, block 256 — exact cover of 11008 x 32)
__global__ void init_out_kernel(const float* __restrict__ bias, float* __restrict__ out) {
    int o = blockIdx.x * 256 + threadIdx.x;
    int m = blockIdx.y;
    out[(size_t)m * OUT_F + o] = bias[o];
}

// Pre-pack x into MFMA A-fragments (bf16), fragment-ordered so qgemm's loads
// are lane-contiguous: ws4[kk*128 + j*64 + lane] = 16B frag for
// (k-step kk, acc j in {rows 0-15, rows 16-31}, lane).
// Lane (lm,lq) of frag j holds x[m = lm + 16*j][kk*32 + lq*8 .. +8] as bf16x8.
// 8192 threads total, runs once (~512 KB read, 256 KB written).
__global__ void prepack_a_kernel(const float* __restrict__ x, uint4* __restrict__ ws4) {
    int u  = blockIdx.x * 256 + threadIdx.x;   // 0..8191
    int kk = u >> 6;
    int l  = u & 63;
    int lm = l & 15;
    int lq = l >> 4;
    int kb = kk * 32 + lq * 8;
    #pragma unroll
    for (int j = 0; j < 2; ++j) {
        const float* xp = x + (size_t)(lm + 16 * j) * IN_F + kb;
        union { uint4 q; uint32_t u[4]; } f;
        f.u[0] = pack_bf16(xp[0], xp[1]);
        f.u[1] = pack_bf16(xp[2], xp[3]);
        f.u[2] = pack_bf16(xp[4], xp[5]);
        f.u[3] = pack_bf16(xp[6], xp[7]);
        ws4[(size_t)kk * 128 + j * 64 + l] = f.q;
    }
}

// LDS-staged streaming dequant-GEMM.
// Weight tile [64 rows][32 k] int32 staged via global_load_lds (dwordx4),
// XOR-swizzled chunk order (source-side; linear LDS dest) to kill the 16-way
// bank conflict of the 128-B row stride. A-operands come pre-packed from ws
// as two lane-contiguous 16-B loads per step (no scattered x reads, no
// per-step A packing VALU).
__launch_bounds__(256)
__global__ void qgemm_kernel(const uint4* __restrict__ af,
                             const int* __restrict__ wq,
                             const float* __restrict__ sz,
                             float* __restrict__ out) {
    __shared__ int lds_w[2][64 * 32];   // double-buffered 8-KB weight tiles

    const int bid = blockIdx.x;
    const int ks  = bid & (NSPLIT - 1);
    const int nb  = bid >> 3;
    const int t   = threadIdx.x;
    const int wv  = t >> 6;
    const int l   = t & 63;
    const int lm  = l & 15;
    const int lq  = l >> 4;

    const int row0 = nb * 64;
    const int row  = row0 + wv * 16 + lm;    // out-feature row this lane computes
    const int k0   = ks * KRANGE;

    // staging: thread t covers tile row rs = t>>3 (+32 for issue 1), chunk
    // slot cs = t&7; fetch global chunk (cs ^ (rs&7)) so LDS slot c of row r
    // holds global chunk c^(r&7) (involution).
    const int rs    = t >> 3;                // 0..31
    const int cs    = t & 7;
    const int* gw0  = wq + (size_t)(row0 + rs) * IN_F + k0 + ((cs ^ (rs & 7)) * 4);
    const int* gw1  = gw0 + (size_t)32 * IN_F;   // rows 32..63

#define STAGE(buf, soff) do {                                                   \
    __builtin_amdgcn_global_load_lds(                                           \
        (const __attribute__((address_space(1))) int*)(gw0 + (soff)),           \
        (__attribute__((address_space(3))) int*)&lds_w[(buf)][wv * 256],        \
        16, 0, 0);                                                              \
    __builtin_amdgcn_global_load_lds(                                           \
        (const __attribute__((address_space(1))) int*)(gw1 + (soff)),           \
        (__attribute__((address_space(3))) int*)&lds_w[(buf)][1024 + wv * 256], \
        16, 0, 0);                                                              \
} while (0)

    // reader addresses (swizzle inverted): lane wants global chunks
    // j0 = 2*lq and j1 = 2*lq+1 of local row rloc.
    const int rloc = wv * 16 + lm;
    const int c0   = rloc * 32 + (((2 * lq)     ^ (rloc & 7)) * 4);
    const int c1   = rloc * 32 + (((2 * lq + 1) ^ (rloc & 7)) * 4);

    const uint4* ap  = af + (size_t)(ks * NSTEP) * 128 + l;   // A-frag stream
    const float* szp = sz + ((size_t)(k0 >> 5) * OUT_F + row) * 2;

    f32x4 acc0 = {0.f, 0.f, 0.f, 0.f};
    f32x4 acc1 = {0.f, 0.f, 0.f, 0.f};

    STAGE(0, 0);
    int cur = 0;
    #pragma unroll 2
    for (int s = 0; s < NSTEP; ++s) {
        __syncthreads();                    // drains vmcnt: buf[cur] is staged
        if (s + 1 < NSTEP) STAGE(cur ^ 1, (s + 1) * 32);   // prefetch next tile

        int4   q0 = *(const int4*)(&lds_w[cur][c0]);
        int4   q1 = *(const int4*)(&lds_w[cur][c1]);
        float2 sv = *(const float2*)(szp);
        union { uint4 q; bf16x8 v; } a0, a1;
        a0.q = ap[0];
        a1.q = ap[64];
        ap  += 128;
        szp += (size_t)OUT_F * 2;

        const float sc = sv.x;
        const float zp = sv.y - 8.0f * sv.x;   // fold the -8 midpoint into zero

        union { bf16x8 v; uint32_t u[4]; } bf;
        bf.u[0] = pack_bf16((float)q0.x * sc + zp, (float)q0.y * sc + zp);
        bf.u[1] = pack_bf16((float)q0.z * sc + zp, (float)q0.w * sc + zp);
        bf.u[2] = pack_bf16((float)q1.x * sc + zp, (float)q1.y * sc + zp);
        bf.u[3] = pack_bf16((float)q1.z * sc + zp, (float)q1.w * sc + zp);

        acc0 = __builtin_amdgcn_mfma_f32_16x16x32_bf16(a0.v, bf.v, acc0, 0, 0, 0);
        acc1 = __builtin_amdgcn_mfma_f32_16x16x32_bf16(a1.v, bf.v, acc1, 0, 0, 0);
        cur ^= 1;
    }
#undef STAGE

    // epilogue: D col(lane&15)=n, row((lane>>4)*4+i)=m  (verified R0)
    const int ocol = row;
    #pragma unroll
    for (int i = 0; i < 4; ++i) {
        int m0 = lq * 4 + i;
        atomicAdd(&out[(size_t)m0 * OUT_F + ocol], acc0[i]);
        atomicAdd(&out[(size_t)(16 + m0) * OUT_F + ocol], acc1[i]);
    }
}

extern "C" void kernel_launch(void* const* d_in, const int* in_sizes, int n_in,
                              void* d_out, int out_size, void* d_ws, size_t ws_size,
                              hipStream_t stream) {
    const float* x    = (const float*)d_in[0];   // [32, 4096] fp32
    const int*   wq   = (const int*)d_in[1];     // [11008, 4096] int32 (0..15)
    const float* sz   = (const float*)d_in[2];   // [128, 11008, 2] fp32
    const float* bias = (const float*)d_in[3];   // [11008] fp32
    float* out = (float*)d_out;                  // [32, 11008] fp32
    uint4* af  = (uint4*)d_ws;                   // [128][2][64] bf16x8 A-frags (256 KB)

    prepack_a_kernel<<<dim3(NKK * 64 / 256), 256, 0, stream>>>(x, af);

    dim3 gi(OUT_F / 256, M_TOK);                 // 43 x 32
    init_out_kernel<<<gi, 256, 0, stream>>>(bias, out);

    dim3 gg((OUT_F / 64) * NSPLIT);              // 172 * 8 = 1376 blocks
    qgemm_kernel<<<gg, 256, 0, stream>>>((const uint4*)af, wq, sz, out);
}

// Round 3
// 272.726 us; speedup vs baseline: 1.0084x; 1.0084x over previous
//
#include <hip/hip_runtime.h>
#include <hip/hip_bf16.h>
#include <stdint.h>

#define M_TOK 32
#define IN_F 4096
#define OUT_F 11008
#define NSPLIT 8
#define KRANGE (IN_F / NSPLIT)   // 512 k per block
#define NSTEP  (KRANGE / 32)     // 16 MFMA k-steps per block
#define NKK    (IN_F / 32)       // 128 global k-steps
#define NBUF   4                 // LDS tile ring (3 tiles in flight)

typedef __attribute__((ext_vector_type(8))) short bf16x8;
typedef __attribute__((ext_vector_type(4))) float f32x4;

__device__ inline uint32_t pack_bf16(float a, float b) {
    __hip_bfloat16 ha = __float2bfloat16(a);
    __hip_bfloat16 hb = __float2bfloat16(b);
    uint16_t ua = *(uint16_t*)&ha;
    uint16_t ub = *(uint16_t*)&hb;
    return (uint32_t)ua | ((uint32_t)ub << 16);
}

// out[m][o] = bias[o]   (grid: 43 x 32, block 256 — exact cover of 11008 x 32)
__global__ void init_out_kernel(const float* __restrict__ bias, float* __restrict__ out) {
    int o = blockIdx.x * 256 + threadIdx.x;
    int m = blockIdx.y;
    out[(size_t)m * OUT_F + o] = bias[o];
}

// Pre-pack x into MFMA A-fragments (bf16), fragment-ordered:
// ws4[kk*128 + j*64 + lane] ; lane (lm,lq) of frag j holds
// x[m = lm + 16*j][kk*32 + lq*8 .. +8] as bf16x8.
__global__ void prepack_a_kernel(const float* __restrict__ x, uint4* __restrict__ ws4) {
    int u  = blockIdx.x * 256 + threadIdx.x;   // 0..8191
    int kk = u >> 6;
    int l  = u & 63;
    int lm = l & 15;
    int lq = l >> 4;
    int kb = kk * 32 + lq * 8;
    #pragma unroll
    for (int j = 0; j < 2; ++j) {
        const float* xp = x + (size_t)(lm + 16 * j) * IN_F + kb;
        union { uint4 q; uint32_t u[4]; } f;
        f.u[0] = pack_bf16(xp[0], xp[1]);
        f.u[1] = pack_bf16(xp[2], xp[3]);
        f.u[2] = pack_bf16(xp[4], xp[5]);
        f.u[3] = pack_bf16(xp[6], xp[7]);
        ws4[(size_t)kk * 128 + j * 64 + l] = f.q;
    }
}

// Deep-pipelined LDS-staged dequant-GEMM (T3/T4: counted vmcnt + raw barrier).
// 4-buffer LDS ring, 3 weight tiles in flight; loads stay outstanding ACROSS
// barriers (never vmcnt(0) in the main loop). Per step:
//   vmcnt(4)  -> oldest tile's 2 staged loads done (4 younger outstanding)
//   s_barrier -> all waves' waits passed => tile visible; prev tile readers done
//   STAGE(s+3) into buf[(s+3)&3] (= tile s-1's buffer, now safe)
//   ds_read + dequant + 2x MFMA
// Per-step A/sz global loads are consumed within the step (compiler-inserted
// waits), so the manual vmcnt count stays exact; sched_barrier(0) pins order.
__launch_bounds__(256)
__global__ void qgemm_kernel(const uint4* __restrict__ af,
                             const int* __restrict__ wq,
                             const float* __restrict__ sz,
                             float* __restrict__ out) {
    __shared__ int lds_w[NBUF][64 * 32];   // 4 x 8 KB weight tiles

    const int bid = blockIdx.x;
    const int ks  = bid & (NSPLIT - 1);
    const int nb  = bid >> 3;
    const int t   = threadIdx.x;
    const int wv  = t >> 6;
    const int l   = t & 63;
    const int lm  = l & 15;
    const int lq  = l >> 4;

    const int row0 = nb * 64;
    const int row  = row0 + wv * 16 + lm;    // out-feature row this lane computes
    const int k0   = ks * KRANGE;

    // staging: thread t covers tile row rs = t>>3 (+32 for issue 1), chunk
    // slot cs = t&7; fetch global chunk (cs ^ (rs&7)) so LDS slot c of row r
    // holds global chunk c^(r&7) (involution; kills 16-way read conflict).
    const int rs    = t >> 3;                // 0..31
    const int cs    = t & 7;
    const int* gw0  = wq + (size_t)(row0 + rs) * IN_F + k0 + ((cs ^ (rs & 7)) * 4);
    const int* gw1  = gw0 + (size_t)32 * IN_F;   // rows 32..63

#define STAGE(buf, tile) do {                                                   \
    __builtin_amdgcn_global_load_lds(                                           \
        (const __attribute__((address_space(1))) int*)(gw0 + (tile) * 32),      \
        (__attribute__((address_space(3))) int*)&lds_w[(buf)][wv * 256],        \
        16, 0, 0);                                                              \
    __builtin_amdgcn_global_load_lds(                                           \
        (const __attribute__((address_space(1))) int*)(gw1 + (tile) * 32),      \
        (__attribute__((address_space(3))) int*)&lds_w[(buf)][1024 + wv * 256], \
        16, 0, 0);                                                              \
} while (0)

#define WAITV(N) do {                                                           \
    asm volatile("s_waitcnt vmcnt(" #N ")" ::: "memory");                       \
    __builtin_amdgcn_sched_barrier(0);                                          \
} while (0)

#define BAR() do {                                                              \
    __builtin_amdgcn_s_barrier();                                               \
    __builtin_amdgcn_sched_barrier(0);                                          \
} while (0)

    // reader addresses (swizzle inverted): lane wants global chunks
    // j0 = 2*lq and j1 = 2*lq+1 of local row rloc.
    const int rloc = wv * 16 + lm;
    const int c0   = rloc * 32 + (((2 * lq)     ^ (rloc & 7)) * 4);
    const int c1   = rloc * 32 + (((2 * lq + 1) ^ (rloc & 7)) * 4);

    const uint4* ap  = af + (size_t)(ks * NSTEP) * 128 + l;   // A-frag stream
    const float* szp = sz + ((size_t)(k0 >> 5) * OUT_F + row) * 2;

    f32x4 acc0 = {0.f, 0.f, 0.f, 0.f};
    f32x4 acc1 = {0.f, 0.f, 0.f, 0.f};

#define STEP_BODY(cb) do {                                                      \
    int4   q0 = *(const int4*)(&lds_w[(cb)][c0]);                               \
    int4   q1 = *(const int4*)(&lds_w[(cb)][c1]);                               \
    float2 sv = *(const float2*)(szp);                                          \
    union { uint4 q; bf16x8 v; } a0, a1;                                        \
    a0.q = ap[0];                                                               \
    a1.q = ap[64];                                                              \
    ap  += 128;                                                                 \
    szp += (size_t)OUT_F * 2;                                                   \
    const float sc = sv.x;                                                      \
    const float zp = sv.y - 8.0f * sv.x;                                        \
    union { bf16x8 v; uint32_t u[4]; } bf;                                      \
    bf.u[0] = pack_bf16((float)q0.x * sc + zp, (float)q0.y * sc + zp);          \
    bf.u[1] = pack_bf16((float)q0.z * sc + zp, (float)q0.w * sc + zp);          \
    bf.u[2] = pack_bf16((float)q1.x * sc + zp, (float)q1.y * sc + zp);          \
    bf.u[3] = pack_bf16((float)q1.z * sc + zp, (float)q1.w * sc + zp);          \
    acc0 = __builtin_amdgcn_mfma_f32_16x16x32_bf16(a0.v, bf.v, acc0, 0, 0, 0);  \
    acc1 = __builtin_amdgcn_mfma_f32_16x16x32_bf16(a1.v, bf.v, acc1, 0, 0, 0);  \
} while (0)

    // prologue: 3 tiles in flight (6 outstanding staged loads per wave)
    STAGE(0, 0);
    STAGE(1, 1);
    STAGE(2, 2);

    // main: steps 0..11, stage tiles 3..14
    #pragma unroll 4
    for (int s = 0; s < 12; ++s) {
        WAITV(4);                        // tile s staged (tiles s+1,s+2 in flight)
        BAR();
        STAGE((s + 3) & 3, s + 3);       // overwrites tile s-1's buffer (safe)
        STEP_BODY(s & 3);
    }
    // step 12: stage the last tile (15)
    WAITV(4); BAR(); STAGE(3, 15); STEP_BODY(0);
    // steps 13..15: drain
    WAITV(4); BAR(); STEP_BODY(1);
    WAITV(2); BAR(); STEP_BODY(2);
    WAITV(0); BAR(); STEP_BODY(3);

#undef STEP_BODY
#undef STAGE
#undef WAITV
#undef BAR

    // epilogue: D col(lane&15)=n, row((lane>>4)*4+i)=m  (verified R0)
    const int ocol = row;
    #pragma unroll
    for (int i = 0; i < 4; ++i) {
        int m0 = lq * 4 + i;
        atomicAdd(&out[(size_t)m0 * OUT_F + ocol], acc0[i]);
        atomicAdd(&out[(size_t)(16 + m0) * OUT_F + ocol], acc1[i]);
    }
}

extern "C" void kernel_launch(void* const* d_in, const int* in_sizes, int n_in,
                              void* d_out, int out_size, void* d_ws, size_t ws_size,
                              hipStream_t stream) {
    const float* x    = (const float*)d_in[0];   // [32, 4096] fp32
    const int*   wq   = (const int*)d_in[1];     // [11008, 4096] int32 (0..15)
    const float* sz   = (const float*)d_in[2];   // [128, 11008, 2] fp32
    const float* bias = (const float*)d_in[3];   // [11008] fp32
    float* out = (float*)d_out;                  // [32, 11008] fp32
    uint4* af  = (uint4*)d_ws;                   // [128][2][64] bf16x8 A-frags (256 KB)

    prepack_a_kernel<<<dim3(NKK * 64 / 256), 256, 0, stream>>>(x, af);

    dim3 gi(OUT_F / 256, M_TOK);                 // 43 x 32
    init_out_kernel<<<gi, 256, 0, stream>>>(bias, out);

    dim3 gg((OUT_F / 64) * NSPLIT);              // 172 * 8 = 1376 blocks
    qgemm_kernel<<<gg, 256, 0, stream>>>((const uint4*)af, wq, sz, out);
}

// Round 4
// 265.820 us; speedup vs baseline: 1.0346x; 1.0260x over previous
//
#include <hip/hip_runtime.h>
#include <hip/hip_bf16.h>
#include <stdint.h>

#define M_TOK 32
#define IN_F 4096
#define OUT_F 11008
#define NSPLIT 8
#define KRANGE (IN_F / NSPLIT)   // 512 k per block
#define NSTEP  (KRANGE / 32)     // 16 MFMA k-steps per block
#define NKK    (IN_F / 32)       // 128 global k-steps
#define NBUF   4                 // weight LDS tile ring (3 tiles in flight)

typedef __attribute__((ext_vector_type(8))) short bf16x8;
typedef __attribute__((ext_vector_type(4))) float f32x4;

__device__ inline uint32_t pack_bf16(float a, float b) {
    __hip_bfloat16 ha = __float2bfloat16(a);
    __hip_bfloat16 hb = __float2bfloat16(b);
    uint16_t ua = *(uint16_t*)&ha;
    uint16_t ub = *(uint16_t*)&hb;
    return (uint32_t)ua | ((uint32_t)ub << 16);
}

// out[m][o] = bias[o]   (grid: 43 x 32, block 256 — exact cover of 11008 x 32)
__global__ void init_out_kernel(const float* __restrict__ bias, float* __restrict__ out) {
    int o = blockIdx.x * 256 + threadIdx.x;
    int m = blockIdx.y;
    out[(size_t)m * OUT_F + o] = bias[o];
}

// Pre-pack x into MFMA A-fragments (bf16), fragment-ordered:
// ws4[kk*128 + j*64 + lane] ; lane (lm,lq) of frag j holds
// x[m = lm + 16*j][kk*32 + lq*8 .. +8] as bf16x8.
__global__ void prepack_a_kernel(const float* __restrict__ x, uint4* __restrict__ ws4) {
    int u  = blockIdx.x * 256 + threadIdx.x;   // 0..8191
    int kk = u >> 6;
    int l  = u & 63;
    int lm = l & 15;
    int lq = l >> 4;
    int kb = kk * 32 + lq * 8;
    #pragma unroll
    for (int j = 0; j < 2; ++j) {
        const float* xp = x + (size_t)(lm + 16 * j) * IN_F + kb;
        union { uint4 q; uint32_t u[4]; } f;
        f.u[0] = pack_bf16(xp[0], xp[1]);
        f.u[1] = pack_bf16(xp[2], xp[3]);
        f.u[2] = pack_bf16(xp[4], xp[5]);
        f.u[3] = pack_bf16(xp[6], xp[7]);
        ws4[(size_t)kk * 128 + j * 64 + l] = f.q;
    }
}

// Deep-pipelined dequant-GEMM. The MAIN LOOP'S ONLY VMEM ops are the staged
// weight loads, so the counted vmcnt(4) is exact (R3 bug: per-step global
// A/sz loads sat behind the staged tiles in the in-order vmcnt queue, so the
// compiler's waits for them drained the whole pipeline every step).
//   prologue: stage A-frags (32 KB) + sz slice (8 KB) + weight tiles 0-2
//   per step: vmcnt(4) -> s_barrier -> STAGE(s+3) -> ds_reads+dequant+2 MFMA
// LDS: 32 KB weights (4-ring) + 32 KB A + 8 KB sz = 72 KB -> 2 blocks/CU.
__launch_bounds__(256)
__global__ void qgemm_kernel(const uint4* __restrict__ af,
                             const int* __restrict__ wq,
                             const float* __restrict__ sz,
                             float* __restrict__ out) {
    __shared__ int    lds_w[NBUF][64 * 32];   // 4 x 8 KB weight tiles
    __shared__ uint4  lds_a[NSTEP * 128];     // 32 KB A-fragments (this ks slice)
    __shared__ float2 lds_s[NSTEP * 64];      // 8 KB scale/zero (step-major)

    const int bid = blockIdx.x;
    const int ks  = bid & (NSPLIT - 1);
    const int nb  = bid >> 3;
    const int t   = threadIdx.x;
    const int wv  = t >> 6;
    const int l   = t & 63;
    const int lm  = l & 15;
    const int lq  = l >> 4;

    const int row0 = nb * 64;
    const int row  = row0 + wv * 16 + lm;    // out-feature row this lane computes
    const int k0   = ks * KRANGE;

    // weight staging: thread t covers tile row rs = t>>3 (+32 for issue 1),
    // chunk slot cs = t&7; fetch global chunk (cs ^ (rs&7)) so LDS slot c of
    // row r holds global chunk c^(r&7) (involution; kills 16-way read conflict).
    const int rs    = t >> 3;                // 0..31
    const int cs    = t & 7;
    const int* gw0  = wq + (size_t)(row0 + rs) * IN_F + k0 + ((cs ^ (rs & 7)) * 4);
    const int* gw1  = gw0 + (size_t)32 * IN_F;   // rows 32..63

#define GLL(src, dst) \
    __builtin_amdgcn_global_load_lds( \
        (const __attribute__((address_space(1))) int*)(src), \
        (__attribute__((address_space(3))) int*)(dst), 16, 0, 0)

#define STAGE(buf, tile) do {                                 \
    GLL(gw0 + (tile) * 32, &lds_w[(buf)][wv * 256]);          \
    GLL(gw1 + (tile) * 32, &lds_w[(buf)][1024 + wv * 256]);   \
} while (0)

#define WAITV(N) do {                                         \
    asm volatile("s_waitcnt vmcnt(" #N ")" ::: "memory");     \
    __builtin_amdgcn_sched_barrier(0);                        \
} while (0)

#define BAR() do {                                            \
    __builtin_amdgcn_s_barrier();                             \
    __builtin_amdgcn_sched_barrier(0);                        \
} while (0)

    // weight reader addresses (swizzle inverted): lane wants global chunks
    // 2*lq and 2*lq+1 of local row rloc.
    const int rloc = wv * 16 + lm;
    const int c0   = rloc * 32 + (((2 * lq)     ^ (rloc & 7)) * 4);
    const int c1   = rloc * 32 + (((2 * lq + 1) ^ (rloc & 7)) * 4);

    // ---- prologue staging (order matters for the vmcnt ledger) ----
    // A-frags: ks slice = af[ks*2048 .. +2048) uint4, contiguous 32 KB.
    {
        const uint4* asrc = af + (size_t)ks * (NSTEP * 128) + t;
        #pragma unroll
        for (int i = 0; i < 8; ++i)
            GLL(asrc + i * 256, &lds_a[i * 256 + wv * 64]);
    }
    // sz: step st, rows row0..row0+63 => 512 B contiguous per step.
    // thread t: st = t>>5 (+8 for issue 1), 16-B chunk c = t&31.
    {
        const float* szsrc = sz + ((size_t)(k0 >> 5) * OUT_F + row0) * 2
                                + (size_t)(t >> 5) * OUT_F * 2 + (t & 31) * 4;
        GLL(szsrc,                        &lds_s[wv * 128]);
        GLL(szsrc + (size_t)8 * OUT_F * 2, &lds_s[512 + wv * 128]);
    }
    STAGE(0, 0);
    STAGE(1, 1);
    STAGE(2, 2);
    __builtin_amdgcn_sched_barrier(0);
    // outstanding: A(8) + sz(2) + w(6) = 16. First WAITV(4) retires A, sz, tile0.

    f32x4 acc0 = {0.f, 0.f, 0.f, 0.f};
    f32x4 acc1 = {0.f, 0.f, 0.f, 0.f};

#define STEP_BODY(cb, st) do {                                                  \
    int4   q0 = *(const int4*)(&lds_w[(cb)][c0]);                               \
    int4   q1 = *(const int4*)(&lds_w[(cb)][c1]);                               \
    union { uint4 q; bf16x8 v; } a0, a1;                                        \
    a0.q = lds_a[(st) * 128 + l];                                               \
    a1.q = lds_a[(st) * 128 + 64 + l];                                          \
    float2 sv = lds_s[(st) * 64 + rloc];                                        \
    const float sc = sv.x;                                                      \
    const float zp = sv.y - 8.0f * sv.x;                                        \
    union { bf16x8 v; uint32_t u[4]; } bf;                                      \
    bf.u[0] = pack_bf16((float)q0.x * sc + zp, (float)q0.y * sc + zp);          \
    bf.u[1] = pack_bf16((float)q0.z * sc + zp, (float)q0.w * sc + zp);          \
    bf.u[2] = pack_bf16((float)q1.x * sc + zp, (float)q1.y * sc + zp);          \
    bf.u[3] = pack_bf16((float)q1.z * sc + zp, (float)q1.w * sc + zp);          \
    acc0 = __builtin_amdgcn_mfma_f32_16x16x32_bf16(a0.v, bf.v, acc0, 0, 0, 0);  \
    acc1 = __builtin_amdgcn_mfma_f32_16x16x32_bf16(a1.v, bf.v, acc1, 0, 0, 0);  \
} while (0)

    // main: steps 0..11, stage tiles 3..14; tiles s+1,s+2,(s+3) stay in flight
    #pragma unroll 4
    for (int s = 0; s < 12; ++s) {
        WAITV(4);                        // tile s staged; 4 loads outstanding
        BAR();
        STAGE((s + 3) & 3, s + 3);       // overwrites tile s-1's buffer (safe)
        STEP_BODY(s & 3, s);
    }
    // step 12: stage the last tile (15)
    WAITV(4); BAR(); STAGE(3, 15); STEP_BODY(0, 12);
    // steps 13..15: drain
    WAITV(4); BAR(); STEP_BODY(1, 13);
    WAITV(2); BAR(); STEP_BODY(2, 14);
    WAITV(0); BAR(); STEP_BODY(3, 15);

#undef STEP_BODY
#undef STAGE
#undef GLL
#undef WAITV
#undef BAR

    // epilogue: D col(lane&15)=n, row((lane>>4)*4+i)=m  (verified R0)
    const int ocol = row;
    #pragma unroll
    for (int i = 0; i < 4; ++i) {
        int m0 = lq * 4 + i;
        atomicAdd(&out[(size_t)m0 * OUT_F + ocol], acc0[i]);
        atomicAdd(&out[(size_t)(16 + m0) * OUT_F + ocol], acc1[i]);
    }
}

extern "C" void kernel_launch(void* const* d_in, const int* in_sizes, int n_in,
                              void* d_out, int out_size, void* d_ws, size_t ws_size,
                              hipStream_t stream) {
    const float* x    = (const float*)d_in[0];   // [32, 4096] fp32
    const int*   wq   = (const int*)d_in[1];     // [11008, 4096] int32 (0..15)
    const float* sz   = (const float*)d_in[2];   // [128, 11008, 2] fp32
    const float* bias = (const float*)d_in[3];   // [11008] fp32
    float* out = (float*)d_out;                  // [32, 11008] fp32
    uint4* af  = (uint4*)d_ws;                   // [128][2][64] bf16x8 A-frags (256 KB)

    prepack_a_kernel<<<dim3(NKK * 64 / 256), 256, 0, stream>>>(x, af);

    dim3 gi(OUT_F / 256, M_TOK);                 // 43 x 32
    init_out_kernel<<<gi, 256, 0, stream>>>(bias, out);

    dim3 gg((OUT_F / 64) * NSPLIT);              // 172 * 8 = 1376 blocks
    qgemm_kernel<<<gg, 256, 0, stream>>>((const uint4*)af, wq, sz, out);
}